// Round 4
// baseline (450.879 us; speedup 1.0000x reference)
//
#include <hip/hip_runtime.h>

// LoKr: out = x @ (W + 2*scalar*(A kron B))^T  with B (16,1)
// => out[m,r] = (x@W^T)[m,r] + 2*scalar*B[r&15] * (x@A^T)[m, r>>4]
//
// R6 = R5 dataflow + T3/T4 sync (raw s_barrier + COUNTED vmcnt).
// R5 post-mortem: __syncthreads drains vmcnt(0) -> every step pays full HBM
// latency serially (3300 cy/step, all pipes <12%). Here every per-iter vmem
// op is issued in FIXED program order (asm volatile / GLDS builtin):
//   [lgkm(0); s_barrier; GLDS(S+1)x2; W(S+2); A(S+2);
//    vmcnt(6) -> xls[BF] ready (W(S+1) STAYS in flight);
//    ds_read+MFMA; vmcnt(4) -> W(S+1)/A(S+1) ready; convert -> wls[BF^1]]
// Counts uniform for all iters incl. first (prologue pre-issues W0,A0
// (drained), G0, W1, A1). sched_barrier(0) after each counted wait keeps
// register-only converts from hoisting above the wait (rule #18).
//  - 8 m-waves x BN=32, BK=64, W/A via LDS (144B-stride, conflict-free),
//    x via global_load_lds with XOR-pre-swizzled source (wave-private rows).
//  - No partials, no reduce kernel; direct fp32 out store.

#define M_DIM 128
#define N_DIM 8192
#define K_DIM 8192
#define BN 32
#define BK 64
#define NSTEP (K_DIM / BK)   // 128

typedef __attribute__((ext_vector_type(8))) short bf16x8;   // 8 bf16 = 4 VGPRs
typedef __attribute__((ext_vector_type(4))) float f32x4;    // MFMA acc

__device__ __forceinline__ unsigned short f2bf(float f) {
  unsigned u = __builtin_bit_cast(unsigned, f);
  u += 0x7FFFu + ((u >> 16) & 1u);   // round-to-nearest-even
  return (unsigned short)(u >> 16);
}

__global__ void convert_x_kernel(const float4* __restrict__ x4,
                                 ushort4* __restrict__ xb4) {
  int t = blockIdx.x * blockDim.x + threadIdx.x;
  const int n4 = M_DIM * K_DIM / 4;  // 262144
  for (int i = t; i < n4; i += gridDim.x * blockDim.x) {
    float4 v = x4[i];
    ushort4 o;
    o.x = f2bf(v.x); o.y = f2bf(v.y); o.z = f2bf(v.z); o.w = f2bf(v.w);
    xb4[i] = o;
  }
}

// fixed-order vmem ops (asm volatile => compiler cannot reorder among them)
#define GLW(dst, p) asm volatile("global_load_dwordx4 %0, %1, off" \
                                 : "=&v"(dst) : "v"(p) : "memory")
#define GLA(dst, p) asm volatile("global_load_dwordx2 %0, %1, off" \
                                 : "=&v"(dst) : "v"(p) : "memory")
#define WAITV(n) { asm volatile("s_waitcnt vmcnt(" #n ")" ::: "memory"); \
                   __builtin_amdgcn_sched_barrier(0); }
#define WAITL0   asm volatile("s_waitcnt lgkmcnt(0)" ::: "memory")

// stage x tile (16KB) for k-offset KOFF into buffer BUF: 2x1KB per wave
#define GLDS2(KOFF, BUF) { \
    __builtin_amdgcn_global_load_lds( \
        (const __attribute__((address_space(1))) unsigned int*)(xs0 + (KOFF)), \
        (__attribute__((address_space(3))) unsigned int*)(&xls[BUF][wv * 1024]), 16, 0, 0); \
    __builtin_amdgcn_global_load_lds( \
        (const __attribute__((address_space(1))) unsigned int*)(xs1 + (KOFF)), \
        (__attribute__((address_space(3))) unsigned int*)(&xls[BUF][wv * 1024 + 512]), 16, 0, 0); \
  }

#define CONVW(BFW, WREG) { ushort4 o; \
    o.x = f2bf(WREG.x); o.y = f2bf(WREG.y); \
    o.z = f2bf(WREG.z); o.w = f2bf(WREG.w); \
    *(ushort4*)&wls[BFW][t >> 4][(t & 15) * 4] = o; }

#define CONVA(BFW, AREG) if (wv == 0) { ushort2 o2; \
    o2.x = f2bf(AREG.x); o2.y = f2bf(AREG.y); \
    *(ushort2*)&wls[BFW][32 + (lane >> 5)][(lane & 31) * 2] = o2; }

// one BK=64 K-step. WCUR/ACUR = fp32 tile S+1 (to convert), WNEW <- tile S+2.
#define ITER(S, BF, WCUR, ACUR, WNEW, ANEW) { \
    WAITL0; \
    __builtin_amdgcn_s_barrier(); \
    { int kx = ((S) + 1 < NSTEP ? (S) + 1 : NSTEP - 1) * BK; \
      GLDS2(kx, (BF) ^ 1); } \
    { int kn = ((S) + 2 < NSTEP ? (S) + 2 : NSTEP - 1) * BK; \
      GLW(WNEW, Wp + kn); \
      GLA(ANEW, Apt + kn); } \
    WAITV(6);  /* xls[BF],wls[BF] sources done; W(S+1),A(S+1) STILL in flight */ \
    _Pragma("unroll") \
    for (int kk = 0; kk < 2; ++kk) { \
      bf16x8 xf = *(const bf16x8*)&xls[BF][(wv * 16 + l15) * BK + (((kk * 4 + l4) ^ (l15 & 7)) * 8)]; \
      bf16x8 w0 = *(const bf16x8*)&wls[BF][l15][kk * 32 + l4 * 8]; \
      bf16x8 w1 = *(const bf16x8*)&wls[BF][16 + l15][kk * 32 + l4 * 8]; \
      bf16x8 af = *(const bf16x8*)&wls[BF][32 + (l15 >> 3)][kk * 32 + l4 * 8]; \
      accW0 = __builtin_amdgcn_mfma_f32_16x16x32_bf16(xf, w0, accW0, 0, 0, 0); \
      accW1 = __builtin_amdgcn_mfma_f32_16x16x32_bf16(xf, w1, accW1, 0, 0, 0); \
      accY  = __builtin_amdgcn_mfma_f32_16x16x32_bf16(xf, af, accY, 0, 0, 0); \
    } \
    WAITV(4);  /* W(S+1)/A(S+1) arrived (this iter's 4 vmem remain) */ \
    CONVW((BF) ^ 1, WCUR); \
    CONVA((BF) ^ 1, ACUR); \
  }

__global__ __launch_bounds__(512) void lokr_main(
    const float* __restrict__ W,           // 8192 x 8192
    const float* __restrict__ A,           // 512 x 8192
    const float* __restrict__ Bv,          // 16
    const float* __restrict__ scal,        // 1
    const unsigned short* __restrict__ xb, // x as bf16, 128 x 8192
    float* __restrict__ out)               // 128 x 8192 fp32
{
  __shared__ unsigned short xls[2][M_DIM * BK];   // 2 x 16 KB, XOR-swizzled
  __shared__ unsigned short wls[2][34][72];       // 2 x 4.9 KB, 144B stride

  const int t    = threadIdx.x;
  const int lane = t & 63;
  const int wv   = t >> 6;          // wave 0..7 = m-frag (rows 16wv..16wv+15)
  const int b    = blockIdx.x;      // n-tile: out cols [32b, 32b+32)
  const int l15  = lane & 15;
  const int l4   = lane >> 4;

  const float sB = 2.0f * scal[0] * Bv[l15];

  // W staging: thread t -> W row 32b+(t>>4), float4 chunk t&15 (contiguous)
  const float* Wp  = W + (size_t)(b * BN + (t >> 4)) * K_DIM + (t & 15) * 4;
  // A staging: WAVE-UNIFORM load (all 8 waves, identical addresses -> L1-hit)
  // so per-wave vmcnt counts match; only wave 0 converts/writes to LDS.
  const float* Apt = A + (size_t)(2 * b + (lane >> 5)) * K_DIM + (lane & 31) * 2;

  // x glds sources: chunk j of wave covers rows wv*16+j*8+(lane>>3);
  // source 16B-chunk = (lane&7) ^ (row&7)  (involution; reader re-XORs)
  const int xr0 = wv * 16 + (lane >> 3);
  const int xr1 = xr0 + 8;
  const int xc  = lane & 7;
  const unsigned short* xs0 = xb + (size_t)xr0 * K_DIM + ((xc ^ (xr0 & 7)) * 8);
  const unsigned short* xs1 = xb + (size_t)xr1 * K_DIM + ((xc ^ (xr1 & 7)) * 8);

  f32x4 accW0 = {0.f, 0.f, 0.f, 0.f};
  f32x4 accW1 = {0.f, 0.f, 0.f, 0.f};
  f32x4 accY  = {0.f, 0.f, 0.f, 0.f};

  // ---- prologue ----
  float4 wA, wB;
  float2 aA, aB;
  GLW(wA, Wp);                 // W(0)
  GLA(aA, Apt);                // A(0)
  WAITV(0);
  CONVW(0, wA);                // tile 0 -> wls[0]
  CONVA(0, aA);
  GLDS2(0, 0);                 // G(0) -> xls[0]
  GLW(wA, Wp + BK);            // W(1)   (wA free after convert)
  GLA(aA, Apt + BK);           // A(1)
  // outstanding: G(0)a, G(0)b, W(1), A(1)  -> iter 0 counts are steady-state

  for (int s2 = 0; s2 < NSTEP; s2 += 2) {
    ITER(s2,     0, wA, aA, wB, aB);
    ITER(s2 + 1, 1, wB, aB, wA, aA);
  }

  // ---- epilogue: fold y2, direct store (no cross-wave reduction) ----
  // C-layout: m = wv*16 + l4*4 + r, col = 32b + nf*16 + l15.
  // accY cols 0-7 = y2[m,2b], cols 8-15 = y2[m,2b+1]; col group nf -> nf<<3.
  const size_t ob = (size_t)(wv * 16 + l4 * 4) * N_DIM + (size_t)b * BN + l15;
#pragma unroll
  for (int nf = 0; nf < 2; ++nf) {
    f32x4 aw = nf ? accW1 : accW0;
#pragma unroll
    for (int r = 0; r < 4; ++r) {
      float y2v = __shfl(accY[r], (lane & 48) | (nf << 3), 64);
      out[ob + (size_t)r * N_DIM + nf * 16] = aw[r] + sB * y2v;
    }
  }
}

extern "C" void kernel_launch(void* const* d_in, const int* in_sizes, int n_in,
                              void* d_out, int out_size, void* d_ws, size_t ws_size,
                              hipStream_t stream) {
  const float* x    = (const float*)d_in[0];   // 128 x 8192
  const float* W    = (const float*)d_in[1];   // 8192 x 8192
  const float* A    = (const float*)d_in[2];   // 512 x 8192
  const float* Bv   = (const float*)d_in[3];   // 16
  const float* scal = (const float*)d_in[4];   // 1
  float* out = (float*)d_out;

  // ws layout: [0, 2MB) x as bf16
  unsigned short* xb = (unsigned short*)d_ws;

  convert_x_kernel<<<512, 256, 0, stream>>>((const float4*)x, (ushort4*)xb);
  lokr_main<<<N_DIM / BN, 512, 0, stream>>>(W, A, Bv, scal, xb, out);
}